// Round 2
// 461.265 us; speedup vs baseline: 1.0000x; 1.0000x over previous
//
#include <hip/hip_runtime.h>
#include <math.h>

// Problem constants (fixed by the reference).
constexpr int Bn = 8192;
constexpr int Nn = 128;
constexpr int Mn = 64;
constexpr float kEPS = 1e-8f;

// R2: register-resident memory tile (R1) + shuffle-based circular shift.
//
// R1 post-mortem: writing lwg[t]/lwg[t+64] then reading lwg[(t±1)&127] in the
// same wave with no barrier is a cross-lane LDS hazard. Compiler alias
// analysis is per-thread (write idx t+64 vs read idx (t+1)&127 are provably
// unequal for one thread), so it may reorder the ds_read before the ds_write;
// the cross-LANE dependency is invisible. Fix: the shift neighbors now come
// from __shfl (register exchange) — the lwg array is gone entirely.
//
// Tile layout: stg[i] = gm4[t + 256*i] puts thread t on rows rbase+16*i
// (rbase = t>>4), column group c4 = t&15 — exactly what the erase/add +
// read-GEMV phase consumes. Per-row dot/||.||^2 reduce over the 16 lanes of a
// row group via __shfl_xor. LDS total 5120 B.

__global__ __launch_bounds__(256, 4)
void ntm_step(const float* __restrict__ memory,
              const float* __restrict__ prev_w,
              const float* __restrict__ kvec,
              const float* __restrict__ beta,
              const float* __restrict__ gate,
              const float* __restrict__ shift,
              const float* __restrict__ gamma,
              const float* __restrict__ erase,
              const float* __restrict__ addv,
              float* __restrict__ out_read,
              float* __restrict__ out_mem,
              float* __restrict__ out_w)
{
  __shared__ float llog[Nn];             // beta * cos
  __shared__ float lw[Nn];               // final weighting
  __shared__ float lpart[16 * Mn];       // read-GEMV partials, 4096 B

  const int b = blockIdx.x;
  const int t = threadIdx.x;
  const int c4 = t & 15;       // fixed 4-column group per thread
  const int rbase = t >> 4;    // rows rbase + 16*i

  const float4* gm4 = (const float4*)(memory + (size_t)b * (Nn * Mn));

  // Issue all global loads up front so they overlap.
  float4 stg[8];
  #pragma unroll
  for (int i = 0; i < 8; ++i) stg[i] = gm4[t + 256 * i];
  const float4 k4 = ((const float4*)(kvec  + (size_t)b * Mn))[c4];
  const float4 ev = ((const float4*)(erase + (size_t)b * Mn))[c4];
  const float4 av = ((const float4*)(addv  + (size_t)b * Mn))[c4];

  // --- content addressing: per-row dot & norms via 16-lane shuffle tree ---
  {
    float dotp[8], sqp[8];
    float ksq = k4.x * k4.x + k4.y * k4.y + k4.z * k4.z + k4.w * k4.w;
    #pragma unroll
    for (int i = 0; i < 8; ++i) {
      const float4 v = stg[i];
      dotp[i] = v.x * k4.x + v.y * k4.y + v.z * k4.z + v.w * k4.w;
      sqp[i]  = v.x * v.x + v.y * v.y + v.z * v.z + v.w * v.w;
    }
    #pragma unroll
    for (int o = 1; o < 16; o <<= 1) {
      ksq += __shfl_xor(ksq, o);
      #pragma unroll
      for (int i = 0; i < 8; ++i) {
        dotp[i] += __shfl_xor(dotp[i], o);
        sqp[i]  += __shfl_xor(sqp[i], o);
      }
    }
    if (c4 == 0) {
      // ksq reduced over 16 groups x 4 elems = full ||k||^2
      const float kn = fmaxf(sqrtf(ksq), kEPS);
      const float bv = beta[b];
      #pragma unroll
      for (int i = 0; i < 8; ++i) {
        const float mn = fmaxf(sqrtf(sqp[i]), kEPS);
        llog[rbase + 16 * i] = bv * (dotp[i] / (kn * mn));
      }
    }
  }
  __syncthreads();

  // --- softmax + interpolation + shift + sharpen (wave 0 only, all
  //     cross-lane traffic via register shuffles — no LDS hazards) ---
  if (t < 64) {
    const float v0 = llog[t], v1 = llog[t + 64];
    float mx = fmaxf(v0, v1);
    #pragma unroll
    for (int o = 1; o < 64; o <<= 1) mx = fmaxf(mx, __shfl_xor(mx, o));
    const float e0 = __expf(v0 - mx), e1 = __expf(v1 - mx);
    float sum = e0 + e1;
    #pragma unroll
    for (int o = 1; o < 64; o <<= 1) sum += __shfl_xor(sum, o);
    const float inv = 1.f / sum;
    const float gv = gate[b];
    // wg0 = position t, wg1 = position t+64 of the 128-length weighting
    const float wg0 = gv * (e0 * inv) + (1.f - gv) * prev_w[b * Nn + t];
    const float wg1 = gv * (e1 * inv) + (1.f - gv) * prev_w[b * Nn + t + 64];

    // circular shift by ±1 over 128 positions held 2-per-lane:
    //   W[n-1] for n0=t   : lane t-1 wg0, except t==0  -> W[127] = lane63 wg1
    //   W[n+1] for n0=t   : lane t+1 wg0, except t==63 -> W[64]  = lane0  wg1
    //   W[n-1] for n1=t+64: lane t-1 wg1, except t==0  -> W[63]  = lane63 wg0
    //   W[n+1] for n1=t+64: lane t+1 wg1, except t==63 -> W[0]   = lane0  wg0
    const int lm1 = (t + 63) & 63;
    const int lp1 = (t + 1) & 63;
    const float a0 = __shfl(wg0, lm1), a1 = __shfl(wg1, lm1);
    const float b0 = __shfl(wg0, lp1), b1 = __shfl(wg1, lp1);
    const float wm0 = (t == 0)  ? a1 : a0;
    const float wp0i = (t == 63) ? b1 : b0;
    const float wm1 = (t == 0)  ? a0 : a1;
    const float wp1i = (t == 63) ? b0 : b1;

    const float s0 = shift[0], s1 = shift[1], s2 = shift[2];
    const float wt0 = s0 * wm0 + s1 * wg0 + s2 * wp0i;
    const float wt1 = s0 * wm1 + s1 * wg1 + s2 * wp1i;

    // sharpen + renormalize
    const float yv = gamma[b];
    const float wp0 = powf(wt0, yv);
    const float wp1 = powf(wt1, yv);
    float psum = wp0 + wp1;
    #pragma unroll
    for (int o = 1; o < 64; o <<= 1) psum += __shfl_xor(psum, o);
    const float pinv = 1.f / psum;
    const float w0 = wp0 * pinv, w1 = wp1 * pinv;
    lw[t]      = w0;
    lw[t + 64] = w1;
    out_w[b * Nn + t]      = w0;
    out_w[b * Nn + t + 64] = w1;
  }
  __syncthreads();

  // --- erase/add write (from OLD memory, register tile) fused with
  //     read-GEMV partials ---
  {
    float4* om4 = (float4*)(out_mem + (size_t)b * (Nn * Mn));
    float4 racc = make_float4(0.f, 0.f, 0.f, 0.f);
    #pragma unroll
    for (int i = 0; i < 8; ++i) {
      const int row = rbase + 16 * i;
      const float wv = lw[row];                       // broadcast (16 lanes/addr)
      const float4 mv = stg[i];
      float4 o;
      o.x = mv.x * (1.f - wv * ev.x) + wv * av.x;
      o.y = mv.y * (1.f - wv * ev.y) + wv * av.y;
      o.z = mv.z * (1.f - wv * ev.z) + wv * av.z;
      o.w = mv.w * (1.f - wv * ev.w) + wv * av.w;
      om4[t + 256 * i] = o;                           // coalesced float4 store
      racc.x += wv * mv.x;
      racc.y += wv * mv.y;
      racc.z += wv * mv.z;
      racc.w += wv * mv.w;
    }
    ((float4*)lpart)[rbase * 16 + c4] = racc;
  }
  __syncthreads();

  // --- combine 16 read partials per column ---
  if (t < Mn) {
    float acc = 0.f;
    #pragma unroll
    for (int p = 0; p < 16; ++p) acc += lpart[p * Mn + t];
    out_read[b * Mn + t] = acc;
  }
}

extern "C" void kernel_launch(void* const* d_in, const int* in_sizes, int n_in,
                              void* d_out, int out_size, void* d_ws, size_t ws_size,
                              hipStream_t stream) {
  const float* memory = (const float*)d_in[0];
  const float* prev_w = (const float*)d_in[1];
  const float* k      = (const float*)d_in[2];
  const float* beta   = (const float*)d_in[3];
  const float* g      = (const float*)d_in[4];
  const float* s      = (const float*)d_in[5];
  const float* y      = (const float*)d_in[6];
  const float* e      = (const float*)d_in[7];
  const float* a      = (const float*)d_in[8];

  float* out = (float*)d_out;
  // return order: read (B*M), mem_new (B*N*M), w (B*N)
  float* out_read = out;
  float* out_mem  = out + (size_t)Bn * Mn;
  float* out_w    = out + (size_t)Bn * Mn + (size_t)Bn * Nn * Mn;

  ntm_step<<<Bn, 256, 0, stream>>>(memory, prev_w, k, beta, g, s, y, e, a,
                                   out_read, out_mem, out_w);
}